// Round 1
// baseline (336.258 us; speedup 1.0000x reference)
//
#include <hip/hip_runtime.h>
#include <hip/hip_bf16.h>
#include <math.h>

// Problem constants
#define BH 1
#define GH 64
#define GW 64
#define CC 384
#define NHD 6
#define KW 7
#define DH 64
#define NTOK (GH*GW)          // 4096
#define LN_EPS 1e-6f

// ---------------------------------------------------------------------------
// Kernel 1: m = silu(cond) @ ada_w + ada_b    (cond [384], ada_w [384,2304])
// ---------------------------------------------------------------------------
__global__ __launch_bounds__(256) void ada_k(const float* __restrict__ cond,
                                             const float* __restrict__ aw,
                                             const float* __restrict__ ab,
                                             float* __restrict__ m)
{
    __shared__ float s[CC];
    int tid = threadIdx.x;
    for (int i = tid; i < CC; i += 256) {
        float c = cond[i];
        s[i] = c / (1.f + expf(-c));          // silu
    }
    __syncthreads();
    int j = blockIdx.x * 256 + tid;           // 0..2303
    float acc = ab[j];
    for (int i = 0; i < CC; ++i)
        acc += s[i] * aw[i * (6*CC) + j];     // coalesced across j
    m[j] = acc;
}

// ---------------------------------------------------------------------------
// Kernel 2: y = LN(x) * (1 + sc) + sh   (one block of 128 per token)
// ---------------------------------------------------------------------------
__global__ __launch_bounds__(128) void ln_mod_k(const float* __restrict__ xin,
                                                const float* __restrict__ sh,
                                                const float* __restrict__ sc,
                                                float* __restrict__ yout)
{
    int t = blockIdx.x;
    int tid = threadIdx.x;
    const float* xr = xin + (size_t)t * CC;
    float v0 = xr[tid], v1 = xr[tid + 128], v2 = xr[tid + 256];
    float s  = v0 + v1 + v2;
    float ss = v0*v0 + v1*v1 + v2*v2;
    #pragma unroll
    for (int off = 32; off; off >>= 1) {
        s  += __shfl_down(s,  off);
        ss += __shfl_down(ss, off);
    }
    __shared__ float red[4];
    int wid = tid >> 6;
    if ((tid & 63) == 0) { red[wid*2] = s; red[wid*2+1] = ss; }
    __syncthreads();
    s  = red[0] + red[2];
    ss = red[1] + red[3];
    float mean = s * (1.f / CC);
    float var  = ss * (1.f / CC) - mean * mean;
    float rstd = rsqrtf(var + LN_EPS);
    float* yr = yout + (size_t)t * CC;
    yr[tid      ] = (v0 - mean) * rstd * (1.f + sc[tid      ]) + sh[tid      ];
    yr[tid + 128] = (v1 - mean) * rstd * (1.f + sc[tid + 128]) + sh[tid + 128];
    yr[tid + 256] = (v2 - mean) * rstd * (1.f + sc[tid + 256]) + sh[tid + 256];
}

// ---------------------------------------------------------------------------
// Kernel 3: generic f32 tiled GEMM  out[M,N] = A[M,K] @ B[K,N]  + epilogue
// BM=BN=64, BK=16, 256 threads, 4x4 register tile per thread.
// EPI: 0 = +bias ; 1 = resid + g*( +bias) ; 2 = gelu(+bias) ; 3 = same as 1
// ---------------------------------------------------------------------------
#define BM 64
#define BN 64
#define BK 16

template<int EPI>
__global__ __launch_bounds__(256) void gemm_k(const float* __restrict__ A,
                                              const float* __restrict__ Bw,
                                              const float* __restrict__ bias,
                                              const float* __restrict__ resid,
                                              const float* __restrict__ gvec,
                                              float* __restrict__ out,
                                              int M, int N, int Kd)
{
    __shared__ float As[BK][BM + 4];   // transposed A tile, padded (16B-aligned rows)
    __shared__ float Bs[BK][BN];
    int tid = threadIdx.x;
    int bx = blockIdx.x, by = blockIdx.y;
    int tx = tid & 15, ty = tid >> 4;
    int row0 = by * BM + ty * 4;
    int col0 = bx * BN + tx * 4;

    int a_r  = tid >> 2;          // 0..63 row in tile
    int a_k4 = (tid & 3) * 4;     // k offset (float4)
    int b_k  = tid >> 4;          // 0..15
    int b_c4 = (tid & 15) * 4;    // col offset (float4)

    float acc[4][4] = {};

    for (int k0 = 0; k0 < Kd; k0 += BK) {
        float4 av = *(const float4*)&A[(size_t)(by*BM + a_r) * Kd + k0 + a_k4];
        As[a_k4+0][a_r] = av.x;
        As[a_k4+1][a_r] = av.y;
        As[a_k4+2][a_r] = av.z;
        As[a_k4+3][a_r] = av.w;
        float4 bv = *(const float4*)&Bw[(size_t)(k0 + b_k) * N + bx*BN + b_c4];
        *(float4*)&Bs[b_k][b_c4] = bv;
        __syncthreads();
        #pragma unroll
        for (int kk = 0; kk < BK; ++kk) {
            float4 a4 = *(const float4*)&As[kk][ty*4];
            float4 b4 = *(const float4*)&Bs[kk][tx*4];
            acc[0][0] += a4.x*b4.x; acc[0][1] += a4.x*b4.y; acc[0][2] += a4.x*b4.z; acc[0][3] += a4.x*b4.w;
            acc[1][0] += a4.y*b4.x; acc[1][1] += a4.y*b4.y; acc[1][2] += a4.y*b4.z; acc[1][3] += a4.y*b4.w;
            acc[2][0] += a4.z*b4.x; acc[2][1] += a4.z*b4.y; acc[2][2] += a4.z*b4.z; acc[2][3] += a4.z*b4.w;
            acc[3][0] += a4.w*b4.x; acc[3][1] += a4.w*b4.y; acc[3][2] += a4.w*b4.z; acc[3][3] += a4.w*b4.w;
        }
        __syncthreads();
    }

    #pragma unroll
    for (int i = 0; i < 4; ++i) {
        int row = row0 + i;
        #pragma unroll
        for (int j = 0; j < 4; ++j) {
            int col = col0 + j;
            float v = acc[i][j] + bias[col];
            size_t idx = (size_t)row * N + col;
            if (EPI == 0) {
                out[idx] = v;
            } else if (EPI == 1 || EPI == 3) {
                out[idx] = resid[idx] + gvec[col] * v;
            } else if (EPI == 2) {
                float u = 0.7978845608028654f * (v + 0.044715f * v * v * v);
                out[idx] = 0.5f * v * (1.f + tanhf(u));
            }
        }
    }
}

// ---------------------------------------------------------------------------
// Kernel 4: NATTEN 7x7 clamped-window attention.
// One wave per (token, head). qkv layout: [tok][q(384) k(384) v(384)].
// ---------------------------------------------------------------------------
__global__ __launch_bounds__(256) void natten_k(const float* __restrict__ qkv,
                                                float* __restrict__ o)
{
    __shared__ float qs[4][DH];
    __shared__ float ps[4][64];
    int tid  = threadIdx.x;
    int w    = tid >> 6;
    int lane = tid & 63;
    int gw   = blockIdx.x * 4 + w;
    int head = gw % NHD;
    int token = gw / NHD;
    int hrow = token >> 6, wcol = token & 63;
    int sh = min(max(hrow - 3, 0), GH - KW);
    int sw = min(max(wcol - 3, 0), GW - KW);

    // stage q (scaled) into LDS
    qs[w][lane] = qkv[(size_t)token * (3*CC) + head * DH + lane] * 0.125f;
    __syncthreads();

    // phase 1: lane j (<49) computes score_j = q . k_j
    float score = -INFINITY;
    if (lane < KW*KW) {
        int jr = lane / KW, jc = lane % KW;
        int ntok = (sh + jr) * GW + (sw + jc);
        const float4* k4 = (const float4*)(qkv + (size_t)ntok * (3*CC) + CC + head * DH);
        const float4* q4 = (const float4*)qs[w];
        float acc = 0.f;
        #pragma unroll
        for (int i = 0; i < DH/4; ++i) {
            float4 a = q4[i], b = k4[i];
            acc += a.x*b.x + a.y*b.y + a.z*b.z + a.w*b.w;
        }
        score = acc;
    }
    // phase 2: wave softmax over 64 lanes (inactive = -inf)
    float mx = score;
    #pragma unroll
    for (int off = 32; off; off >>= 1) mx = fmaxf(mx, __shfl_xor(mx, off));
    float p = (lane < KW*KW) ? expf(score - mx) : 0.f;
    float sm = p;
    #pragma unroll
    for (int off = 32; off; off >>= 1) sm += __shfl_xor(sm, off);
    p /= sm;
    ps[w][lane] = p;
    __syncthreads();

    // phase 3: lane = d accumulates over 49 neighbors (coalesced v reads)
    float od = 0.f;
    #pragma unroll 7
    for (int j = 0; j < KW*KW; ++j) {
        int jr = j / KW, jc = j % KW;
        int ntok = (sh + jr) * GW + (sw + jc);
        od += ps[w][j] * qkv[(size_t)ntok * (3*CC) + 2*CC + head * DH + lane];
    }
    o[(size_t)token * CC + head * DH + lane] = od;
}

// ---------------------------------------------------------------------------
// launch
// ---------------------------------------------------------------------------
extern "C" void kernel_launch(void* const* d_in, const int* in_sizes, int n_in,
                              void* d_out, int out_size, void* d_ws, size_t ws_size,
                              hipStream_t stream)
{
    const float* x      = (const float*)d_in[0];
    const float* cond   = (const float*)d_in[1];
    const float* qkv_w  = (const float*)d_in[2];
    const float* qkv_b  = (const float*)d_in[3];
    const float* proj_w = (const float*)d_in[4];
    const float* proj_b = (const float*)d_in[5];
    const float* fc1_w  = (const float*)d_in[6];
    const float* fc1_b  = (const float*)d_in[7];
    const float* fc2_w  = (const float*)d_in[8];
    const float* fc2_b  = (const float*)d_in[9];
    const float* ada_w  = (const float*)d_in[10];
    const float* ada_b  = (const float*)d_in[11];
    float* out = (float*)d_out;
    float* ws  = (float*)d_ws;

    // scratch layout (floats); "big" is shared by qkv (4096x1152) and hdn (4096x1536)
    float* m      = ws;                         // 2304
    float* y      = m + 6*CC;                   // 4096*384
    float* big    = y + (size_t)NTOK*CC;        // 4096*1536
    float* attn_o = big + (size_t)NTOK*(4*CC);  // 4096*384
    float* qkv    = big;
    float* hdn    = big;

    const float* sh_a = m;
    const float* sc_a = m + CC;
    const float* g_a  = m + 2*CC;
    const float* sh_m = m + 3*CC;
    const float* sc_m = m + 4*CC;
    const float* g_m  = m + 5*CC;

    // 1. adaLN modulation vector
    ada_k<<<(6*CC)/256, 256, 0, stream>>>(cond, ada_w, ada_b, m);
    // 2. y = LN(x)*(1+sc_a)+sh_a
    ln_mod_k<<<NTOK, 128, 0, stream>>>(x, sh_a, sc_a, y);
    // 3. qkv = y @ qkv_w + qkv_b
    gemm_k<0><<<dim3((3*CC)/BN, NTOK/BM), 256, 0, stream>>>(
        y, qkv_w, qkv_b, nullptr, nullptr, qkv, NTOK, 3*CC, CC);
    // 4. neighborhood attention
    natten_k<<<(NTOK*NHD)/4, 256, 0, stream>>>(qkv, attn_o);
    // 5. x1 = x + g_a * (attn_o @ proj_w + proj_b)   -> d_out
    gemm_k<1><<<dim3(CC/BN, NTOK/BM), 256, 0, stream>>>(
        attn_o, proj_w, proj_b, x, g_a, out, NTOK, CC, CC);
    // 6. y = LN(x1)*(1+sc_m)+sh_m
    ln_mod_k<<<NTOK, 128, 0, stream>>>(out, sh_m, sc_m, y);
    // 7. hdn = gelu(y @ fc1_w + fc1_b)
    gemm_k<2><<<dim3((4*CC)/BN, NTOK/BM), 256, 0, stream>>>(
        y, fc1_w, fc1_b, nullptr, nullptr, hdn, NTOK, 4*CC, CC);
    // 8. out = x1 + g_m * (hdn @ fc2_w + fc2_b)      (in-place on d_out)
    gemm_k<3><<<dim3(CC/BN, NTOK/BM), 256, 0, stream>>>(
        hdn, fc2_w, fc2_b, out, g_m, out, NTOK, CC, 4*CC);
}

// Round 2
// 150.866 us; speedup vs baseline: 2.2288x; 2.2288x over previous
//
#include <hip/hip_runtime.h>
#include <hip/hip_bf16.h>
#include <math.h>

// Problem constants
#define GH 64
#define GW 64
#define CC 384
#define NHD 6
#define KW 7
#define DH 64
#define NTOK (GH*GW)          // 4096
#define LN_EPS 1e-6f

typedef __attribute__((ext_vector_type(4))) float f32x4;
typedef __attribute__((ext_vector_type(8))) short bf16x8;
typedef __hip_bfloat16 bf16;

__device__ __forceinline__ float bf2f(unsigned int u16) {
    union { unsigned int i; float f; } c; c.i = u16 << 16; return c.f;
}
__device__ __forceinline__ bf16 f2bf(float f) { return __float2bfloat16(f); }

// ---------------------------------------------------------------------------
// Kernel 1: m = silu(cond) @ ada_w + ada_b    (cond [384], ada_w [384,2304])
// ---------------------------------------------------------------------------
__global__ __launch_bounds__(256) void ada_k(const float* __restrict__ cond,
                                             const float* __restrict__ aw,
                                             const float* __restrict__ ab,
                                             float* __restrict__ m)
{
    __shared__ float s[CC];
    int tid = threadIdx.x;
    for (int i = tid; i < CC; i += 256) {
        float c = cond[i];
        s[i] = c / (1.f + expf(-c));          // silu
    }
    __syncthreads();
    int j = blockIdx.x * 256 + tid;           // 0..2303
    float acc = ab[j];
    for (int i = 0; i < CC; ++i)
        acc += s[i] * aw[i * (6*CC) + j];     // coalesced across j
    m[j] = acc;
}

// ---------------------------------------------------------------------------
// Kernel 2: weight transpose+convert: out[n][k] = bf16(in[k][n])
// block (32,8), grid (N/32, K/32)
// ---------------------------------------------------------------------------
__global__ __launch_bounds__(256) void wt_k(const float* __restrict__ in,
                                            bf16* __restrict__ out,
                                            int K, int N)
{
    __shared__ float t[32][33];
    int bn = blockIdx.x * 32, bk = blockIdx.y * 32;
    int x = threadIdx.x, y = threadIdx.y;       // 32, 8
    #pragma unroll
    for (int i = 0; i < 32; i += 8)
        t[y + i][x] = in[(size_t)(bk + y + i) * N + bn + x];
    __syncthreads();
    #pragma unroll
    for (int i = 0; i < 32; i += 8)
        out[(size_t)(bn + y + i) * K + bk + x] = f2bf(t[x][y + i]);
}

// ---------------------------------------------------------------------------
// Kernel 3: y = LN(x) * (1 + sc) + sh   -> bf16   (one block of 128 per token)
// ---------------------------------------------------------------------------
__global__ __launch_bounds__(128) void ln_mod_k(const float* __restrict__ xin,
                                                const float* __restrict__ sh,
                                                const float* __restrict__ sc,
                                                bf16* __restrict__ yout)
{
    int t = blockIdx.x;
    int tid = threadIdx.x;
    const float* xr = xin + (size_t)t * CC;
    float v0 = xr[tid], v1 = xr[tid + 128], v2 = xr[tid + 256];
    float s  = v0 + v1 + v2;
    float ss = v0*v0 + v1*v1 + v2*v2;
    #pragma unroll
    for (int off = 32; off; off >>= 1) {
        s  += __shfl_down(s,  off);
        ss += __shfl_down(ss, off);
    }
    __shared__ float red[4];
    int wid = tid >> 6;
    if ((tid & 63) == 0) { red[wid*2] = s; red[wid*2+1] = ss; }
    __syncthreads();
    s  = red[0] + red[2];
    ss = red[1] + red[3];
    float mean = s * (1.f / CC);
    float var  = ss * (1.f / CC) - mean * mean;
    float rstd = rsqrtf(var + LN_EPS);
    bf16* yr = yout + (size_t)t * CC;
    yr[tid      ] = f2bf((v0 - mean) * rstd * (1.f + sc[tid      ]) + sh[tid      ]);
    yr[tid + 128] = f2bf((v1 - mean) * rstd * (1.f + sc[tid + 128]) + sh[tid + 128]);
    yr[tid + 256] = f2bf((v2 - mean) * rstd * (1.f + sc[tid + 256]) + sh[tid + 256]);
}

// ---------------------------------------------------------------------------
// Kernel 4: MFMA bf16 GEMM  out[M,N] = A[M,K] @ Bt[N,K]^T  + epilogue
// 128x128 tile, BK=64, 256 threads = 4 waves (2x2), each wave 64x64 (4x4 frags)
// EPI: 0 = +bias (OutT) ; 1 = resid + g*(+bias) ; 2 = gelu(+bias)
// ---------------------------------------------------------------------------
#define GBM 128
#define GBK 64
#define LDKP 72   // padded K stride (bf16 elements): 144B rows -> 2-way conflicts only

template<int EPI, typename OutT>
__global__ __launch_bounds__(256) void mgemm_k(const bf16* __restrict__ A,   // [M][K]
                                               const bf16* __restrict__ Bt,  // [N][K]
                                               const float* __restrict__ bias,
                                               const float* __restrict__ resid,
                                               const float* __restrict__ gvec,
                                               OutT* __restrict__ out,
                                               int M, int N, int Kd)
{
    __shared__ bf16 As[GBM][LDKP];
    __shared__ bf16 Bs[GBM][LDKP];
    int tid = threadIdx.x;
    int wid = tid >> 6, lane = tid & 63;
    int wm = wid >> 1, wn = wid & 1;
    int row_base = blockIdx.y * GBM;
    int col_base = blockIdx.x * GBM;

    int r_st  = tid >> 3;          // 0..31 (4 passes cover 128 rows)
    int kc_st = (tid & 7) * 8;     // k element offset, 16B chunks

    f32x4 acc[4][4] = {};

    for (int k0 = 0; k0 < Kd; k0 += GBK) {
        #pragma unroll
        for (int i = 0; i < 4; ++i) {
            int r = r_st + i * 32;
            uint4 va = *(const uint4*)&A [(size_t)(row_base + r) * Kd + k0 + kc_st];
            *(uint4*)&As[r][kc_st] = va;
            uint4 vb = *(const uint4*)&Bt[(size_t)(col_base + r) * Kd + k0 + kc_st];
            *(uint4*)&Bs[r][kc_st] = vb;
        }
        __syncthreads();
        #pragma unroll
        for (int kk = 0; kk < GBK; kk += 32) {
            bf16x8 af[4], bfr[4];
            #pragma unroll
            for (int m = 0; m < 4; ++m)
                af[m]  = *(const bf16x8*)&As[wm*64 + m*16 + (lane & 15)][kk + (lane >> 4) * 8];
            #pragma unroll
            for (int n = 0; n < 4; ++n)
                bfr[n] = *(const bf16x8*)&Bs[wn*64 + n*16 + (lane & 15)][kk + (lane >> 4) * 8];
            #pragma unroll
            for (int m = 0; m < 4; ++m)
                #pragma unroll
                for (int n = 0; n < 4; ++n)
                    acc[m][n] = __builtin_amdgcn_mfma_f32_16x16x32_bf16(af[m], bfr[n], acc[m][n], 0, 0, 0);
        }
        __syncthreads();
    }

    // epilogue: C/D layout col=lane&15, row=(lane>>4)*4+reg
    int cl = lane & 15, rq = lane >> 4;
    #pragma unroll
    for (int m = 0; m < 4; ++m) {
        #pragma unroll
        for (int n = 0; n < 4; ++n) {
            int col = col_base + wn*64 + n*16 + cl;
            float bv = bias[col];
            float gv = (EPI == 1) ? gvec[col] : 0.f;
            #pragma unroll
            for (int j = 0; j < 4; ++j) {
                int row = row_base + wm*64 + m*16 + rq*4 + j;
                float v = acc[m][n][j] + bv;
                size_t idx = (size_t)row * N + col;
                if (EPI == 0) {
                    out[idx] = (OutT)f2bf(v);   // OutT == bf16 here
                } else if (EPI == 1) {
                    ((float*)out)[idx] = resid[idx] + gv * v;
                } else { // EPI == 2: tanh-gelu
                    float u = 0.7978845608028654f * (v + 0.044715f * v * v * v);
                    out[idx] = (OutT)f2bf(0.5f * v * (1.f + tanhf(u)));
                }
            }
        }
    }
}

// ---------------------------------------------------------------------------
// Kernel 5: NATTEN 7x7 clamped-window attention (bf16 qkv -> bf16 out)
// One wave per (token, head). qkv layout: [tok][q(384) k(384) v(384)]
// ---------------------------------------------------------------------------
__global__ __launch_bounds__(256) void natten_k(const bf16* __restrict__ qkv,
                                                bf16* __restrict__ o)
{
    __shared__ float qs[4][DH];
    __shared__ float ps[4][64];
    int tid  = threadIdx.x;
    int w    = tid >> 6;
    int lane = tid & 63;
    int gw   = blockIdx.x * 4 + w;
    int head = gw % NHD;
    int token = gw / NHD;
    int hrow = token >> 6, wcol = token & 63;
    int sh = min(max(hrow - 3, 0), GH - KW);
    int sw = min(max(wcol - 3, 0), GW - KW);

    qs[w][lane] = __bfloat162float(qkv[(size_t)token * (3*CC) + head * DH + lane]) * 0.125f;
    __syncthreads();

    float score = -INFINITY;
    if (lane < KW*KW) {
        int jr = lane / KW, jc = lane % KW;
        int ntok = (sh + jr) * GW + (sw + jc);
        const uint4* kp = (const uint4*)(qkv + (size_t)ntok * (3*CC) + CC + head * DH);
        const float* qp = qs[w];
        float acc = 0.f;
        #pragma unroll
        for (int i = 0; i < 8; ++i) {
            uint4 kv = kp[i];
            acc += qp[i*8+0] * bf2f(kv.x & 0xffffu) + qp[i*8+1] * bf2f(kv.x >> 16)
                 + qp[i*8+2] * bf2f(kv.y & 0xffffu) + qp[i*8+3] * bf2f(kv.y >> 16)
                 + qp[i*8+4] * bf2f(kv.z & 0xffffu) + qp[i*8+5] * bf2f(kv.z >> 16)
                 + qp[i*8+6] * bf2f(kv.w & 0xffffu) + qp[i*8+7] * bf2f(kv.w >> 16);
        }
        score = acc;
    }
    float mx = score;
    #pragma unroll
    for (int off = 32; off; off >>= 1) mx = fmaxf(mx, __shfl_xor(mx, off));
    float p = (lane < KW*KW) ? expf(score - mx) : 0.f;
    float sm = p;
    #pragma unroll
    for (int off = 32; off; off >>= 1) sm += __shfl_xor(sm, off);
    p /= sm;
    ps[w][lane] = p;
    __syncthreads();

    float od = 0.f;
    #pragma unroll 7
    for (int j = 0; j < KW*KW; ++j) {
        int jr = j / KW, jc = j % KW;
        int ntok = (sh + jr) * GW + (sw + jc);
        od += ps[w][j] * __bfloat162float(qkv[(size_t)ntok * (3*CC) + 2*CC + head * DH + lane]);
    }
    o[(size_t)token * CC + head * DH + lane] = f2bf(od);
}

// ---------------------------------------------------------------------------
// launch
// ---------------------------------------------------------------------------
extern "C" void kernel_launch(void* const* d_in, const int* in_sizes, int n_in,
                              void* d_out, int out_size, void* d_ws, size_t ws_size,
                              hipStream_t stream)
{
    const float* x      = (const float*)d_in[0];
    const float* cond   = (const float*)d_in[1];
    const float* qkv_w  = (const float*)d_in[2];
    const float* qkv_b  = (const float*)d_in[3];
    const float* proj_w = (const float*)d_in[4];
    const float* proj_b = (const float*)d_in[5];
    const float* fc1_w  = (const float*)d_in[6];
    const float* fc1_b  = (const float*)d_in[7];
    const float* fc2_w  = (const float*)d_in[8];
    const float* fc2_b  = (const float*)d_in[9];
    const float* ada_w  = (const float*)d_in[10];
    const float* ada_b  = (const float*)d_in[11];
    float* out = (float*)d_out;

    // scratch layout (bytes)
    char* p = (char*)d_ws;
    float* m       = (float*)p;            p += 6*CC*sizeof(float);
    bf16* y        = (bf16*)p;             p += (size_t)NTOK*CC*2;
    bf16* qkv      = (bf16*)p;             p += (size_t)NTOK*(3*CC)*2;
    bf16* attn_o   = (bf16*)p;             p += (size_t)NTOK*CC*2;
    bf16* hdn      = (bf16*)p;             p += (size_t)NTOK*(4*CC)*2;
    bf16* qkv_wt   = (bf16*)p;             p += (size_t)(3*CC)*CC*2;
    bf16* proj_wt  = (bf16*)p;             p += (size_t)CC*CC*2;
    bf16* fc1_wt   = (bf16*)p;             p += (size_t)(4*CC)*CC*2;
    bf16* fc2_wt   = (bf16*)p;             p += (size_t)CC*(4*CC)*2;

    const float* sh_a = m;
    const float* sc_a = m + CC;
    const float* g_a  = m + 2*CC;
    const float* sh_m = m + 3*CC;
    const float* sc_m = m + 4*CC;
    const float* g_m  = m + 5*CC;

    // 0. weight convert+transpose (f32 [K][N] -> bf16 [N][K])
    wt_k<<<dim3((3*CC)/32, CC/32),   dim3(32,8), 0, stream>>>(qkv_w,  qkv_wt,  CC,   3*CC);
    wt_k<<<dim3(CC/32,     CC/32),   dim3(32,8), 0, stream>>>(proj_w, proj_wt, CC,   CC);
    wt_k<<<dim3((4*CC)/32, CC/32),   dim3(32,8), 0, stream>>>(fc1_w,  fc1_wt,  CC,   4*CC);
    wt_k<<<dim3(CC/32,   (4*CC)/32), dim3(32,8), 0, stream>>>(fc2_w,  fc2_wt,  4*CC, CC);
    // 1. adaLN modulation vector
    ada_k<<<(6*CC)/256, 256, 0, stream>>>(cond, ada_w, ada_b, m);
    // 2. y = LN(x)*(1+sc_a)+sh_a
    ln_mod_k<<<NTOK, 128, 0, stream>>>(x, sh_a, sc_a, y);
    // 3. qkv = y @ qkv_w + qkv_b   (bf16 out)
    mgemm_k<0, bf16><<<dim3((3*CC)/GBM, NTOK/GBM), 256, 0, stream>>>(
        y, qkv_wt, qkv_b, nullptr, nullptr, qkv, NTOK, 3*CC, CC);
    // 4. neighborhood attention
    natten_k<<<(NTOK*NHD)/4, 256, 0, stream>>>(qkv, attn_o);
    // 5. x1 = x + g_a * (attn_o @ proj_w + proj_b)   -> d_out (f32)
    mgemm_k<1, float><<<dim3(CC/GBM, NTOK/GBM), 256, 0, stream>>>(
        attn_o, proj_wt, proj_b, x, g_a, out, NTOK, CC, CC);
    // 6. y = LN(x1)*(1+sc_m)+sh_m
    ln_mod_k<<<NTOK, 128, 0, stream>>>(out, sh_m, sc_m, y);
    // 7. hdn = gelu(y @ fc1_w + fc1_b)  (bf16 out)
    mgemm_k<2, bf16><<<dim3((4*CC)/GBM, NTOK/GBM), 256, 0, stream>>>(
        y, fc1_wt, fc1_b, nullptr, nullptr, hdn, NTOK, 4*CC, CC);
    // 8. out = x1 + g_m * (hdn @ fc2_w + fc2_b)      (in-place on d_out)
    mgemm_k<1, float><<<dim3(CC/GBM, NTOK/GBM), 256, 0, stream>>>(
        hdn, fc2_wt, fc2_b, out, g_m, out, NTOK, CC, 4*CC);
}

// Round 3
// 144.011 us; speedup vs baseline: 2.3349x; 1.0476x over previous
//
#include <hip/hip_runtime.h>
#include <hip/hip_bf16.h>
#include <math.h>

// Problem constants
#define GH 64
#define GW 64
#define CC 384
#define NHD 6
#define KW 7
#define DH 64
#define NTOK (GH*GW)          // 4096
#define LN_EPS 1e-6f

typedef __attribute__((ext_vector_type(4))) float f32x4;
typedef __attribute__((ext_vector_type(8))) short bf16x8;
typedef __hip_bfloat16 bf16;

__device__ __forceinline__ float bf2f(unsigned int u16) {
    union { unsigned int i; float f; } c; c.i = u16 << 16; return c.f;
}
__device__ __forceinline__ bf16 f2bf(float f) { return __float2bfloat16(f); }

// ---------------------------------------------------------------------------
// Kernel 1: m = silu(cond) @ ada_w + ada_b
// 36 blocks: block b handles cols [b*64, b*64+64), 4-way k-split + LDS reduce
// ---------------------------------------------------------------------------
__global__ __launch_bounds__(256) void ada_k(const float* __restrict__ cond,
                                             const float* __restrict__ aw,
                                             const float* __restrict__ ab,
                                             float* __restrict__ m)
{
    __shared__ float s[CC];
    __shared__ float red[4][64];
    int tid = threadIdx.x;
    for (int i = tid; i < CC; i += 256) {
        float c = cond[i];
        s[i] = c / (1.f + expf(-c));          // silu
    }
    __syncthreads();
    int c  = tid & 63;
    int ks = tid >> 6;                        // 0..3
    int col = blockIdx.x * 64 + c;
    float acc = 0.f;
    for (int k = ks * 96; k < (ks + 1) * 96; ++k)
        acc += s[k] * aw[(size_t)k * (6*CC) + col];
    red[ks][c] = acc;
    __syncthreads();
    if (tid < 64)
        m[col] = red[0][c] + red[1][c] + red[2][c] + red[3][c] + ab[col];
}

// ---------------------------------------------------------------------------
// Kernel 2: all 4 weight transposes in ONE dispatch.  out[n][k]=bf16(in[k][n])
// tile counts (32x32 tiles): qkv 36*12=432 | proj 12*12=144 | fc1 48*12=576
//                            | fc2 12*48=576  -> total 1728 blocks
// ---------------------------------------------------------------------------
__global__ __launch_bounds__(256) void wt_all_k(const float* __restrict__ qkv_w,
                                                const float* __restrict__ proj_w,
                                                const float* __restrict__ fc1_w,
                                                const float* __restrict__ fc2_w,
                                                bf16* __restrict__ qkv_wt,
                                                bf16* __restrict__ proj_wt,
                                                bf16* __restrict__ fc1_wt,
                                                bf16* __restrict__ fc2_wt)
{
    __shared__ float t[32][33];
    int b = blockIdx.x;
    const float* in; bf16* outp; int K, N, lid;
    if (b < 432)       { in = qkv_w;  outp = qkv_wt;  K = 384;  N = 1152; lid = b; }
    else if (b < 576)  { in = proj_w; outp = proj_wt; K = 384;  N = 384;  lid = b - 432; }
    else if (b < 1152) { in = fc1_w;  outp = fc1_wt;  K = 384;  N = 1536; lid = b - 576; }
    else               { in = fc2_w;  outp = fc2_wt;  K = 1536; N = 384;  lid = b - 1152; }
    int nbn = N / 32;
    int bn = (lid % nbn) * 32, bk = (lid / nbn) * 32;
    int x = threadIdx.x & 31, y = threadIdx.x >> 5;   // (32,8)
    #pragma unroll
    for (int i = 0; i < 32; i += 8)
        t[y + i][x] = in[(size_t)(bk + y + i) * N + bn + x];
    __syncthreads();
    #pragma unroll
    for (int i = 0; i < 32; i += 8)
        outp[(size_t)(bn + y + i) * K + bk + x] = f2bf(t[x][y + i]);
}

// ---------------------------------------------------------------------------
// Kernel 3: y = LN(x) * (1 + sc) + sh   -> bf16   (one block of 128 per token)
// ---------------------------------------------------------------------------
__global__ __launch_bounds__(128) void ln_mod_k(const float* __restrict__ xin,
                                                const float* __restrict__ sh,
                                                const float* __restrict__ sc,
                                                bf16* __restrict__ yout)
{
    int t = blockIdx.x;
    int tid = threadIdx.x;
    const float* xr = xin + (size_t)t * CC;
    float v0 = xr[tid], v1 = xr[tid + 128], v2 = xr[tid + 256];
    float s  = v0 + v1 + v2;
    float ss = v0*v0 + v1*v1 + v2*v2;
    #pragma unroll
    for (int off = 32; off; off >>= 1) {
        s  += __shfl_down(s,  off);
        ss += __shfl_down(ss, off);
    }
    __shared__ float red[4];
    int wid = tid >> 6;
    if ((tid & 63) == 0) { red[wid*2] = s; red[wid*2+1] = ss; }
    __syncthreads();
    s  = red[0] + red[2];
    ss = red[1] + red[3];
    float mean = s * (1.f / CC);
    float var  = ss * (1.f / CC) - mean * mean;
    float rstd = rsqrtf(var + LN_EPS);
    bf16* yr = yout + (size_t)t * CC;
    yr[tid      ] = f2bf((v0 - mean) * rstd * (1.f + sc[tid      ]) + sh[tid      ]);
    yr[tid + 128] = f2bf((v1 - mean) * rstd * (1.f + sc[tid + 128]) + sh[tid + 128]);
    yr[tid + 256] = f2bf((v2 - mean) * rstd * (1.f + sc[tid + 256]) + sh[tid + 256]);
}

// ---------------------------------------------------------------------------
// Kernel 4: MFMA bf16 GEMM  out[M,N] = A[M,K] @ Bt[N,K]^T  + epilogue
// BMxBN tile, BK=64, 256 threads = 4 waves (2x2), wave tile (BM/2)x(BN/2)
// FM=BM/32, FN=BN/32 fragments of 16x16.
// EPI: 0 = +bias (bf16) ; 1 = resid + g*(+bias) (f32) ; 2 = gelu(+bias) (bf16)
// ---------------------------------------------------------------------------
#define GBK 64
#define LDKP 72   // padded K stride (bf16): 144B rows -> 2-way conflicts only

template<int EPI, typename OutT, int BM, int BN>
__global__ __launch_bounds__(256) void mgemm_k(const bf16* __restrict__ A,   // [M][K]
                                               const bf16* __restrict__ Bt,  // [N][K]
                                               const float* __restrict__ bias,
                                               const float* __restrict__ resid,
                                               const float* __restrict__ gvec,
                                               OutT* __restrict__ out,
                                               int M, int N, int Kd)
{
    constexpr int FM = BM / 32, FN = BN / 32;
    __shared__ bf16 As[BM][LDKP];
    __shared__ bf16 Bs[BN][LDKP];
    int tid = threadIdx.x;
    int wid = tid >> 6, lane = tid & 63;
    int wm = wid >> 1, wn = wid & 1;
    int row_base = blockIdx.y * BM;
    int col_base = blockIdx.x * BN;

    f32x4 acc[FM][FN] = {};

    for (int k0 = 0; k0 < Kd; k0 += GBK) {
        #pragma unroll
        for (int i = 0; i < BM / 32; ++i) {
            int idx = tid + i * 256;
            int r = idx >> 3;
            int kc = (idx & 7) * 8;
            *(uint4*)&As[r][kc] = *(const uint4*)&A [(size_t)(row_base + r) * Kd + k0 + kc];
        }
        #pragma unroll
        for (int i = 0; i < BN / 32; ++i) {
            int idx = tid + i * 256;
            int r = idx >> 3;
            int kc = (idx & 7) * 8;
            *(uint4*)&Bs[r][kc] = *(const uint4*)&Bt[(size_t)(col_base + r) * Kd + k0 + kc];
        }
        __syncthreads();
        #pragma unroll
        for (int kk = 0; kk < GBK; kk += 32) {
            bf16x8 af[FM], bfr[FN];
            #pragma unroll
            for (int m = 0; m < FM; ++m)
                af[m]  = *(const bf16x8*)&As[wm*(BM/2) + m*16 + (lane & 15)][kk + (lane >> 4) * 8];
            #pragma unroll
            for (int n = 0; n < FN; ++n)
                bfr[n] = *(const bf16x8*)&Bs[wn*(BN/2) + n*16 + (lane & 15)][kk + (lane >> 4) * 8];
            #pragma unroll
            for (int m = 0; m < FM; ++m)
                #pragma unroll
                for (int n = 0; n < FN; ++n)
                    acc[m][n] = __builtin_amdgcn_mfma_f32_16x16x32_bf16(af[m], bfr[n], acc[m][n], 0, 0, 0);
        }
        __syncthreads();
    }

    // epilogue: C/D layout col=lane&15, row=(lane>>4)*4+reg
    int cl = lane & 15, rq = lane >> 4;
    #pragma unroll
    for (int m = 0; m < FM; ++m) {
        #pragma unroll
        for (int n = 0; n < FN; ++n) {
            int col = col_base + wn*(BN/2) + n*16 + cl;
            float bv = bias[col];
            float gv = (EPI == 1) ? gvec[col] : 0.f;
            #pragma unroll
            for (int j = 0; j < 4; ++j) {
                int row = row_base + wm*(BM/2) + m*16 + rq*4 + j;
                float v = acc[m][n][j] + bv;
                size_t idx = (size_t)row * N + col;
                if constexpr (EPI == 0) {
                    out[idx] = (OutT)f2bf(v);
                } else if constexpr (EPI == 1) {
                    out[idx] = resid[idx] + gv * v;
                } else { // gelu (tanh approx)
                    float u = 0.7978845608028654f * (v + 0.044715f * v * v * v);
                    out[idx] = (OutT)f2bf(0.5f * v * (1.f + tanhf(u)));
                }
            }
        }
    }
}

// ---------------------------------------------------------------------------
// Kernel 5: NATTEN 7x7 clamped-window attention (bf16 qkv -> bf16 out)
// One wave per (token, head). qkv layout: [tok][q(384) k(384) v(384)]
// ---------------------------------------------------------------------------
__global__ __launch_bounds__(256) void natten_k(const bf16* __restrict__ qkv,
                                                bf16* __restrict__ o)
{
    __shared__ float qs[4][DH];
    __shared__ float ps[4][64];
    int tid  = threadIdx.x;
    int w    = tid >> 6;
    int lane = tid & 63;
    int gw   = blockIdx.x * 4 + w;
    int head = gw % NHD;
    int token = gw / NHD;
    int hrow = token >> 6, wcol = token & 63;
    int sh = min(max(hrow - 3, 0), GH - KW);
    int sw = min(max(wcol - 3, 0), GW - KW);

    qs[w][lane] = __bfloat162float(qkv[(size_t)token * (3*CC) + head * DH + lane]) * 0.125f;
    __syncthreads();

    float score = -INFINITY;
    if (lane < KW*KW) {
        int jr = lane / KW, jc = lane % KW;
        int ntok = (sh + jr) * GW + (sw + jc);
        const uint4* kp = (const uint4*)(qkv + (size_t)ntok * (3*CC) + CC + head * DH);
        const float* qp = qs[w];
        float acc = 0.f;
        #pragma unroll
        for (int i = 0; i < 8; ++i) {
            uint4 kv = kp[i];
            acc += qp[i*8+0] * bf2f(kv.x & 0xffffu) + qp[i*8+1] * bf2f(kv.x >> 16)
                 + qp[i*8+2] * bf2f(kv.y & 0xffffu) + qp[i*8+3] * bf2f(kv.y >> 16)
                 + qp[i*8+4] * bf2f(kv.z & 0xffffu) + qp[i*8+5] * bf2f(kv.z >> 16)
                 + qp[i*8+6] * bf2f(kv.w & 0xffffu) + qp[i*8+7] * bf2f(kv.w >> 16);
        }
        score = acc;
    }
    float mx = score;
    #pragma unroll
    for (int off = 32; off; off >>= 1) mx = fmaxf(mx, __shfl_xor(mx, off));
    float p = (lane < KW*KW) ? expf(score - mx) : 0.f;
    float sm = p;
    #pragma unroll
    for (int off = 32; off; off >>= 1) sm += __shfl_xor(sm, off);
    p /= sm;
    ps[w][lane] = p;
    __syncthreads();

    float od = 0.f;
    #pragma unroll 7
    for (int j = 0; j < KW*KW; ++j) {
        int jr = j / KW, jc = j % KW;
        int ntok = (sh + jr) * GW + (sw + jc);
        od += ps[w][j] * __bfloat162float(qkv[(size_t)ntok * (3*CC) + 2*CC + head * DH + lane]);
    }
    o[(size_t)token * CC + head * DH + lane] = f2bf(od);
}

// ---------------------------------------------------------------------------
// launch
// ---------------------------------------------------------------------------
extern "C" void kernel_launch(void* const* d_in, const int* in_sizes, int n_in,
                              void* d_out, int out_size, void* d_ws, size_t ws_size,
                              hipStream_t stream)
{
    const float* x      = (const float*)d_in[0];
    const float* cond   = (const float*)d_in[1];
    const float* qkv_w  = (const float*)d_in[2];
    const float* qkv_b  = (const float*)d_in[3];
    const float* proj_w = (const float*)d_in[4];
    const float* proj_b = (const float*)d_in[5];
    const float* fc1_w  = (const float*)d_in[6];
    const float* fc1_b  = (const float*)d_in[7];
    const float* fc2_w  = (const float*)d_in[8];
    const float* fc2_b  = (const float*)d_in[9];
    const float* ada_w  = (const float*)d_in[10];
    const float* ada_b  = (const float*)d_in[11];
    float* out = (float*)d_out;

    // scratch layout (bytes)
    char* p = (char*)d_ws;
    float* m       = (float*)p;            p += 6*CC*sizeof(float);
    bf16* y        = (bf16*)p;             p += (size_t)NTOK*CC*2;
    bf16* qkv      = (bf16*)p;             p += (size_t)NTOK*(3*CC)*2;
    bf16* attn_o   = (bf16*)p;             p += (size_t)NTOK*CC*2;
    bf16* hdn      = (bf16*)p;             p += (size_t)NTOK*(4*CC)*2;
    bf16* qkv_wt   = (bf16*)p;             p += (size_t)(3*CC)*CC*2;
    bf16* proj_wt  = (bf16*)p;             p += (size_t)CC*CC*2;
    bf16* fc1_wt   = (bf16*)p;             p += (size_t)(4*CC)*CC*2;
    bf16* fc2_wt   = (bf16*)p;             p += (size_t)CC*(4*CC)*2;

    const float* sh_a = m;
    const float* sc_a = m + CC;
    const float* g_a  = m + 2*CC;
    const float* sh_m = m + 3*CC;
    const float* sc_m = m + 4*CC;
    const float* g_m  = m + 5*CC;

    // 0. all weight transposes (f32 [K][N] -> bf16 [N][K]) in one dispatch
    wt_all_k<<<1728, 256, 0, stream>>>(qkv_w, proj_w, fc1_w, fc2_w,
                                       qkv_wt, proj_wt, fc1_wt, fc2_wt);
    // 1. adaLN modulation vector
    ada_k<<<(6*CC)/64, 256, 0, stream>>>(cond, ada_w, ada_b, m);
    // 2. y = LN(x)*(1+sc_a)+sh_a
    ln_mod_k<<<NTOK, 128, 0, stream>>>(x, sh_a, sc_a, y);
    // 3. qkv = y @ qkv_w + qkv_b   (bf16 out)  grid (9,32)
    mgemm_k<0, bf16, 128, 128><<<dim3((3*CC)/128, NTOK/128), 256, 0, stream>>>(
        y, qkv_wt, qkv_b, nullptr, nullptr, qkv, NTOK, 3*CC, CC);
    // 4. neighborhood attention
    natten_k<<<(NTOK*NHD)/4, 256, 0, stream>>>(qkv, attn_o);
    // 5. x1 = x + g_a * (attn_o @ proj_w + proj_b) -> d_out (f32)  grid (6,64)
    mgemm_k<1, float, 64, 64><<<dim3(CC/64, NTOK/64), 256, 0, stream>>>(
        attn_o, proj_wt, proj_b, x, g_a, out, NTOK, CC, CC);
    // 6. y = LN(x1)*(1+sc_m)+sh_m
    ln_mod_k<<<NTOK, 128, 0, stream>>>(out, sh_m, sc_m, y);
    // 7. hdn = gelu(y @ fc1_w + fc1_b)  (bf16 out)  grid (12,32)
    mgemm_k<2, bf16, 128, 128><<<dim3((4*CC)/128, NTOK/128), 256, 0, stream>>>(
        y, fc1_wt, fc1_b, nullptr, nullptr, hdn, NTOK, 4*CC, CC);
    // 8. out = x1 + g_m * (hdn @ fc2_w + fc2_b)  (in-place, f32)  grid (6,64)
    mgemm_k<1, float, 64, 64><<<dim3(CC/64, NTOK/64), 256, 0, stream>>>(
        hdn, fc2_wt, fc2_b, out, g_m, out, NTOK, CC, 4*CC);
}